// Round 1
// baseline (189.388 us; speedup 1.0000x reference)
//
#include <hip/hip_runtime.h>

#define K_TAPS 9
#define CC 64
#define HH 256
#define WW 256
#define BB 4
#define NN 16384

__device__ __forceinline__ float softplus_f(float x) {
    return fmaxf(x, 0.0f) + log1pf(expf(-fabsf(x)));
}
__device__ __forceinline__ float leaky_f(float x) {
    return x >= 0.0f ? x : 0.2f * x;
}

// transpose (B, C, H*W) -> (B, H*W, C) so that per-position channel reads coalesce
__global__ void __launch_bounds__(256) transpose_kernel(const float* __restrict__ feat,
                                                        float* __restrict__ featT) {
    __shared__ float tile[64][65];
    int b = blockIdx.y;
    int p0 = blockIdx.x * 64;
    int tp = threadIdx.x & 63;
    int tq = threadIdx.x >> 6; // 0..3
    const float* fb = feat + (size_t)b * CC * HH * WW;
#pragma unroll
    for (int i = 0; i < 16; ++i) {
        int c = tq * 16 + i;
        tile[c][tp] = fb[(size_t)c * (HH * WW) + p0 + tp];
    }
    __syncthreads();
    float* ob = featT + ((size_t)b * (HH * WW) + p0) * CC;
#pragma unroll
    for (int i = 0; i < 16; ++i) {
        int p = tq * 16 + i;
        ob[(size_t)p * CC + tp] = tile[tp][p];
    }
}

template <bool TR>
__device__ __forceinline__ float bilin_sample(const float* __restrict__ feat, int b, int lane,
                                              float gx, float gy) {
    float ix = (gx + 1.0f) * 0.5f * (float)(WW - 1);
    float iy = (gy + 1.0f) * 0.5f * (float)(HH - 1);
    ix = fminf(fmaxf(ix, 0.0f), (float)(WW - 1));
    iy = fminf(fmaxf(iy, 0.0f), (float)(HH - 1));
    float x0f = floorf(ix), y0f = floorf(iy);
    float wx = ix - x0f, wy = iy - y0f;
    int x0 = (int)x0f, y0 = (int)y0f;
    int x1 = min(x0 + 1, WW - 1), y1 = min(y0 + 1, HH - 1);
    float f00, f01, f10, f11;
    if (TR) {
        const float* base = feat + (size_t)b * (HH * WW) * CC;
        f00 = base[((size_t)(y0 * WW + x0)) * CC + lane];
        f01 = base[((size_t)(y0 * WW + x1)) * CC + lane];
        f10 = base[((size_t)(y1 * WW + x0)) * CC + lane];
        f11 = base[((size_t)(y1 * WW + x1)) * CC + lane];
    } else {
        const float* base = feat + ((size_t)b * CC + lane) * (HH * WW);
        f00 = base[y0 * WW + x0];
        f01 = base[y0 * WW + x1];
        f10 = base[y1 * WW + x0];
        f11 = base[y1 * WW + x1];
    }
    float omwx = 1.0f - wx, omwy = 1.0f - wy;
    return f00 * omwx * omwy + f01 * wx * omwy + f10 * omwx * wy + f11 * wx * wy;
}

template <bool TR>
__global__ void __launch_bounds__(256) main_kernel(const float* __restrict__ feat,
                                                   const float* __restrict__ coords,
                                                   const float* __restrict__ cell,
                                                   const float* __restrict__ W1,
                                                   const float* __restrict__ b1,
                                                   const float* __restrict__ Wr,
                                                   const float* __restrict__ br,
                                                   const float* __restrict__ W2,
                                                   const float* __restrict__ b2,
                                                   float* __restrict__ out) {
    int lane = threadIdx.x & 63;
    int wave = threadIdx.x >> 6;
    int pidx = blockIdx.x * 4 + wave;
    if (pidx >= BB * NN) return;
    int b = pidx >> 14; // N = 16384

    float gx = coords[(size_t)pidx * 2 + 0];
    float gy = coords[(size_t)pidx * 2 + 1];
    float cx = cell[(size_t)pidx * 2 + 0];
    float cy = cell[(size_t)pidx * 2 + 1];

    // anchor sample: lane = channel
    float fa = bilin_sample<TR>(feat, b, lane, gx, gy);

    // layer 1: h[lane] = leaky(sum_i in[i] * W1[i][lane] + b1[lane])
    float h = b1[lane];
#pragma unroll
    for (int i = 0; i < 64; ++i) {
        float a = __shfl(fa, i, 64);
        h = fmaf(a, W1[i * 64 + lane], h);
    }
    h = fmaf(gx, W1[64 * 64 + lane], h);
    h = fmaf(gy, W1[65 * 64 + lane], h);
    h = fmaf(cx, W1[66 * 64 + lane], h);
    h = fmaf(cy, W1[67 * 64 + lane], h);
    h = leaky_f(h);

    // layer 2: h2 = leaky(h + h @ Wr + br)
    float h2 = br[lane];
#pragma unroll
    for (int i = 0; i < 64; ++i) {
        float a = __shfl(h, i, 64);
        h2 = fmaf(a, Wr[i * 64 + lane], h2);
    }
    h2 = leaky_f(h + h2);

    // layer 3: out[j] for j = lane < 29
    int j = lane < 29 ? lane : 0;
    float o = b2[j];
#pragma unroll
    for (int i = 0; i < 64; ++i) {
        float a = __shfl(h2, i, 64);
        o = fmaf(a, W2[i * 29 + j], o);
    }

    // head post-processing: lanes 0..8 own tap k = lane
    int kk = lane < K_TAPS ? lane : 0;
    float r_raw = __shfl(o, 0, 64);
    float s_raw = __shfl(o, 1, 64);
    float rx_raw = __shfl(o, 2 + 2 * kk, 64);
    float ry_raw = __shfl(o, 3 + 2 * kk, 64);
    float g_raw = __shfl(o, 20 + kk, 64);

    float r = fminf(fmaxf(softplus_f(r_raw) + 0.1f, 0.1f), 4.0f);
    float sg = fminf(fmaxf(softplus_f(s_raw) + 0.5f, 0.5f), 6.0f);
    float bx = (float)(kk % 3 - 1);
    float by = (float)(kk / 3 - 1);
    float offx = fmaf(r, bx, tanhf(rx_raw) * 0.5f);
    float offy = fmaf(r, by, tanhf(ry_raw) * 0.5f);
    float d2 = offx * offx + offy * offy;
    float se = sg * 2.0f;
    float wgeo = expf(-0.5f * d2 / (se * se + 1e-8f));
    float gate = 1.0f / (1.0f + expf(-g_raw));
    float w = wgeo * gate;

    float wv = (lane < K_TAPS) ? w : 0.0f;
#pragma unroll
    for (int m = 32; m >= 1; m >>= 1) wv += __shfl_xor(wv, m, 64);
    float wn = w / (wv + 1e-8f);

    const float SCLX = 2.0f / (float)(WW - 1);
    const float SCLY = 2.0f / (float)(HH - 1);
    float acc = 0.0f;
#pragma unroll
    for (int k = 0; k < K_TAPS; ++k) {
        float ox = __shfl(offx, k, 64) * SCLX;
        float oy = __shfl(offy, k, 64) * SCLY;
        float wk = __shfl(wn, k, 64);
        float fv = bilin_sample<TR>(feat, b, lane, gx + ox, gy + oy);
        acc = fmaf(fv, wk, acc);
    }
    out[(size_t)pidx * CC + lane] = acc;
}

extern "C" void kernel_launch(void* const* d_in, const int* in_sizes, int n_in,
                              void* d_out, int out_size, void* d_ws, size_t ws_size,
                              hipStream_t stream) {
    const float* feat = (const float*)d_in[0];
    const float* coords = (const float*)d_in[1];
    const float* cell = (const float*)d_in[2];
    const float* W1 = (const float*)d_in[3];
    const float* b1 = (const float*)d_in[4];
    const float* Wr = (const float*)d_in[5];
    const float* br = (const float*)d_in[6];
    const float* W2 = (const float*)d_in[7];
    const float* b2 = (const float*)d_in[8];
    float* out = (float*)d_out;

    const size_t needT = (size_t)BB * HH * WW * CC * sizeof(float);
    const int nblocks = (BB * NN) / 4; // 4 waves (points) per block

    if (ws_size >= needT) {
        float* featT = (float*)d_ws;
        dim3 tg((HH * WW) / 64, BB);
        transpose_kernel<<<tg, 256, 0, stream>>>(feat, featT);
        main_kernel<true><<<nblocks, 256, 0, stream>>>(featT, coords, cell, W1, b1, Wr, br, W2,
                                                       b2, out);
    } else {
        main_kernel<false><<<nblocks, 256, 0, stream>>>(feat, coords, cell, W1, b1, Wr, br, W2,
                                                        b2, out);
    }
}

// Round 2
// 153.279 us; speedup vs baseline: 1.2356x; 1.2356x over previous
//
#include <hip/hip_runtime.h>

#define K_TAPS 9
#define CC 64
#define HH 256
#define WW 256
#define BB 4
#define NN 16384
#define SCLX (2.0f / 255.0f)
#define SCLY (2.0f / 255.0f)
#define SWZ(p, c) ((p) ^ ((c) & 31))

__device__ __forceinline__ float softplus_f(float x) {
    return fmaxf(x, 0.0f) + log1pf(expf(-fabsf(x)));
}
__device__ __forceinline__ float leaky_f(float x) { return x >= 0.0f ? x : 0.2f * x; }
__device__ __forceinline__ float clampf(float x, float lo, float hi) {
    return fminf(fmaxf(x, lo), hi);
}

// transpose (B, C, H*W) -> (B, H*W, C)
__global__ void __launch_bounds__(256) transpose_kernel(const float* __restrict__ feat,
                                                        float* __restrict__ featT) {
    __shared__ float tile[64][65];
    int b = blockIdx.y;
    int p0 = blockIdx.x * 64;
    int tp = threadIdx.x & 63;
    int tq = threadIdx.x >> 6;
    const float* fb = feat + (size_t)b * CC * HH * WW;
#pragma unroll
    for (int i = 0; i < 16; ++i) {
        int c = tq * 16 + i;
        tile[c][tp] = fb[(size_t)c * (HH * WW) + p0 + tp];
    }
    __syncthreads();
    float* ob = featT + ((size_t)b * (HH * WW) + p0) * CC;
#pragma unroll
    for (int i = 0; i < 16; ++i) {
        int p = tq * 16 + i;
        ob[(size_t)p * CC + tp] = tile[tp][p];
    }
}

// bilinear sample of 4 channels (one float4) at grid coords (gx,gy) in [-1,1]
__device__ __forceinline__ float4 bilin4(const float4* __restrict__ base, float gx, float gy,
                                         int c4) {
    float ix = clampf((gx + 1.0f) * 0.5f * 255.0f, 0.0f, 255.0f);
    float iy = clampf((gy + 1.0f) * 0.5f * 255.0f, 0.0f, 255.0f);
    float x0f = floorf(ix), y0f = floorf(iy);
    float wx = ix - x0f, wy = iy - y0f;
    int x0 = (int)x0f, y0 = (int)y0f;
    int x1 = min(x0 + 1, 255), y1 = min(y0 + 1, 255);
    float4 f00 = base[((y0 << 8) + x0) * 16 + c4];
    float4 f01 = base[((y0 << 8) + x1) * 16 + c4];
    float4 f10 = base[((y1 << 8) + x0) * 16 + c4];
    float4 f11 = base[((y1 << 8) + x1) * 16 + c4];
    float omx = 1.0f - wx, omy = 1.0f - wy;
    float4 v;
    v.x = (f00.x * omx + f01.x * wx) * omy + (f10.x * omx + f11.x * wx) * wy;
    v.y = (f00.y * omx + f01.y * wx) * omy + (f10.y * omx + f11.y * wx) * wy;
    v.z = (f00.z * omx + f01.z * wx) * omy + (f10.z * omx + f11.z * wx) * wy;
    v.w = (f00.w * omx + f01.w * wx) * omy + (f10.w * omx + f11.w * wx) * wy;
    return v;
}

__global__ void __launch_bounds__(256) fused_kernel(const float4* __restrict__ ft4,
                                                    const float* __restrict__ coords,
                                                    const float* __restrict__ cell,
                                                    const float* __restrict__ W1,
                                                    const float* __restrict__ b1,
                                                    const float* __restrict__ Wr,
                                                    const float* __restrict__ br,
                                                    const float* __restrict__ W2,
                                                    const float* __restrict__ b2,
                                                    float4* __restrict__ out4) {
    __shared__ union {
        float in[64][256];   // [channel][point], XOR-swizzled columns (column t private to thread t)
        float prm[256][29];  // per-point params: 9 x (sx, sy, wn)
    } sm;

    const int t = threadIdx.x;
    const int wave = t >> 6;
    const int lane = t & 63;
    const int dp = lane >> 4;   // point-sub within group of 4
    const int c4 = lane & 15;   // channel quad
    const int c0 = c4 * 4;

    // ---------------- Phase 1: anchor gather (4 points per wave, float4) ----------------
#pragma unroll 4
    for (int g = 0; g < 16; ++g) {
        int pl = wave * 64 + g * 4 + dp;
        int pg = blockIdx.x * 256 + pl;
        int bb = pg >> 14;
        float qx = coords[2 * pg], qy = coords[2 * pg + 1];
        float4 v = bilin4(ft4 + (size_t)bb * (HH * WW) * 16, qx, qy, c4);
        sm.in[c0 + 0][SWZ(pl, c0 + 0)] = v.x;
        sm.in[c0 + 1][SWZ(pl, c0 + 1)] = v.y;
        sm.in[c0 + 2][SWZ(pl, c0 + 2)] = v.z;
        sm.in[c0 + 3][SWZ(pl, c0 + 3)] = v.w;
    }
    __syncthreads();

    // ---------------- Phase 2: MLP, thread = point ----------------
    const int pgt = blockIdx.x * 256 + t;
    const float gx = coords[2 * pgt], gy = coords[2 * pgt + 1];
    const float cx = cell[2 * pgt], cy = cell[2 * pgt + 1];

    // layer 1: h = leaky(in @ W1 + b1)
    float h[64];
#pragma unroll
    for (int j = 0; j < 64; ++j) h[j] = b1[j];
#pragma unroll 2
    for (int i = 0; i < 64; ++i) {
        float a = sm.in[i][SWZ(t, i)];
#pragma unroll
        for (int j = 0; j < 64; ++j) h[j] = fmaf(a, W1[i * 64 + j], h[j]);
    }
    {
        float extra[4] = {gx, gy, cx, cy};
#pragma unroll
        for (int e = 0; e < 4; ++e) {
            float a = extra[e];
#pragma unroll
            for (int j = 0; j < 64; ++j) h[j] = fmaf(a, W1[(64 + e) * 64 + j], h[j]);
        }
    }
#pragma unroll
    for (int j = 0; j < 64; ++j) {
        h[j] = leaky_f(h[j]);
        sm.in[j][SWZ(t, j)] = h[j];  // own column: no barrier needed
    }

    // layer 2: h2 = leaky(h + h @ Wr + br)
    float h2[64];
#pragma unroll
    for (int j = 0; j < 64; ++j) h2[j] = br[j];
#pragma unroll 2
    for (int i = 0; i < 64; ++i) {
        float a = sm.in[i][SWZ(t, i)];
#pragma unroll
        for (int j = 0; j < 64; ++j) h2[j] = fmaf(a, Wr[i * 64 + j], h2[j]);
    }
#pragma unroll
    for (int j = 0; j < 64; ++j) {
        h2[j] = leaky_f(h[j] + h2[j]);
        sm.in[j][SWZ(t, j)] = h2[j];
    }

    // layer 3: out = h2 @ W2 + b2 (29 outputs)
    float o[29];
#pragma unroll
    for (int j = 0; j < 29; ++j) o[j] = b2[j];
#pragma unroll 2
    for (int i = 0; i < 64; ++i) {
        float a = sm.in[i][SWZ(t, i)];
#pragma unroll
        for (int j = 0; j < 29; ++j) o[j] = fmaf(a, W2[i * 29 + j], o[j]);
    }

    __syncthreads();  // all layer-3 LDS reads done before prm overwrites the union

    // ---------------- head: offsets + weights ----------------
    {
        float r = clampf(softplus_f(o[0]) + 0.1f, 0.1f, 4.0f);
        float sg = clampf(softplus_f(o[1]) + 0.5f, 0.5f, 6.0f);
        float se = sg * 2.0f;
        float inv2 = -0.5f / (se * se + 1e-8f);
        float sxk[9], syk[9], wk[9];
        float wsum = 0.0f;
#pragma unroll
        for (int k = 0; k < K_TAPS; ++k) {
            float bx = (float)(k % 3 - 1);
            float by = (float)(k / 3 - 1);
            float ox = fmaf(r, bx, tanhf(o[2 + 2 * k]) * 0.5f);
            float oy = fmaf(r, by, tanhf(o[3 + 2 * k]) * 0.5f);
            float d2 = ox * ox + oy * oy;
            float wgeo = expf(d2 * inv2);
            float gate = 1.0f / (1.0f + expf(-o[20 + k]));
            wk[k] = wgeo * gate;
            wsum += wk[k];
            sxk[k] = fmaf(ox, SCLX, gx);
            syk[k] = fmaf(oy, SCLY, gy);
        }
        float inv = 1.0f / (wsum + 1e-8f);
#pragma unroll
        for (int k = 0; k < K_TAPS; ++k) {
            sm.prm[t][3 * k + 0] = sxk[k];
            sm.prm[t][3 * k + 1] = syk[k];
            sm.prm[t][3 * k + 2] = wk[k] * inv;
        }
    }
    __syncthreads();

    // ---------------- Phase 3: deformable gather (4 points per wave, float4) ----------------
    for (int g = 0; g < 16; ++g) {
        int pl = wave * 64 + g * 4 + dp;
        int pg = blockIdx.x * 256 + pl;
        int bb = pg >> 14;
        const float4* base = ft4 + (size_t)bb * (HH * WW) * 16;
        float4 acc = make_float4(0.0f, 0.0f, 0.0f, 0.0f);
#pragma unroll
        for (int k = 0; k < K_TAPS; ++k) {
            float sx = sm.prm[pl][3 * k + 0];
            float sy = sm.prm[pl][3 * k + 1];
            float wgt = sm.prm[pl][3 * k + 2];
            float4 v = bilin4(base, sx, sy, c4);
            acc.x = fmaf(v.x, wgt, acc.x);
            acc.y = fmaf(v.y, wgt, acc.y);
            acc.z = fmaf(v.z, wgt, acc.z);
            acc.w = fmaf(v.w, wgt, acc.w);
        }
        out4[(size_t)pg * 16 + c4] = acc;
    }
}

// ---------------- fallback (ws too small for transpose): round-1 style ----------------
__device__ __forceinline__ float bilin_chw(const float* __restrict__ feat, int b, int lane,
                                           float gx, float gy) {
    float ix = clampf((gx + 1.0f) * 0.5f * 255.0f, 0.0f, 255.0f);
    float iy = clampf((gy + 1.0f) * 0.5f * 255.0f, 0.0f, 255.0f);
    float x0f = floorf(ix), y0f = floorf(iy);
    float wx = ix - x0f, wy = iy - y0f;
    int x0 = (int)x0f, y0 = (int)y0f;
    int x1 = min(x0 + 1, 255), y1 = min(y0 + 1, 255);
    const float* base = feat + ((size_t)b * CC + lane) * (HH * WW);
    float f00 = base[(y0 << 8) + x0];
    float f01 = base[(y0 << 8) + x1];
    float f10 = base[(y1 << 8) + x0];
    float f11 = base[(y1 << 8) + x1];
    float omx = 1.0f - wx, omy = 1.0f - wy;
    return (f00 * omx + f01 * wx) * omy + (f10 * omx + f11 * wx) * wy;
}

__global__ void __launch_bounds__(256) fallback_kernel(const float* __restrict__ feat,
                                                       const float* __restrict__ coords,
                                                       const float* __restrict__ cell,
                                                       const float* __restrict__ W1,
                                                       const float* __restrict__ b1,
                                                       const float* __restrict__ Wr,
                                                       const float* __restrict__ br,
                                                       const float* __restrict__ W2,
                                                       const float* __restrict__ b2,
                                                       float* __restrict__ out) {
    int lane = threadIdx.x & 63;
    int wave = threadIdx.x >> 6;
    int pidx = blockIdx.x * 4 + wave;
    if (pidx >= BB * NN) return;
    int b = pidx >> 14;
    float gx = coords[(size_t)pidx * 2 + 0];
    float gy = coords[(size_t)pidx * 2 + 1];
    float cx = cell[(size_t)pidx * 2 + 0];
    float cy = cell[(size_t)pidx * 2 + 1];
    float fa = bilin_chw(feat, b, lane, gx, gy);
    float h = b1[lane];
#pragma unroll
    for (int i = 0; i < 64; ++i) {
        float a = __shfl(fa, i, 64);
        h = fmaf(a, W1[i * 64 + lane], h);
    }
    h = fmaf(gx, W1[64 * 64 + lane], h);
    h = fmaf(gy, W1[65 * 64 + lane], h);
    h = fmaf(cx, W1[66 * 64 + lane], h);
    h = fmaf(cy, W1[67 * 64 + lane], h);
    h = leaky_f(h);
    float h2 = br[lane];
#pragma unroll
    for (int i = 0; i < 64; ++i) {
        float a = __shfl(h, i, 64);
        h2 = fmaf(a, Wr[i * 64 + lane], h2);
    }
    h2 = leaky_f(h + h2);
    int j = lane < 29 ? lane : 0;
    float o = b2[j];
#pragma unroll
    for (int i = 0; i < 64; ++i) {
        float a = __shfl(h2, i, 64);
        o = fmaf(a, W2[i * 29 + j], o);
    }
    int kk = lane < K_TAPS ? lane : 0;
    float r_raw = __shfl(o, 0, 64);
    float s_raw = __shfl(o, 1, 64);
    float rx_raw = __shfl(o, 2 + 2 * kk, 64);
    float ry_raw = __shfl(o, 3 + 2 * kk, 64);
    float g_raw = __shfl(o, 20 + kk, 64);
    float r = clampf(softplus_f(r_raw) + 0.1f, 0.1f, 4.0f);
    float sg = clampf(softplus_f(s_raw) + 0.5f, 0.5f, 6.0f);
    float bx = (float)(kk % 3 - 1);
    float by = (float)(kk / 3 - 1);
    float offx = fmaf(r, bx, tanhf(rx_raw) * 0.5f);
    float offy = fmaf(r, by, tanhf(ry_raw) * 0.5f);
    float d2 = offx * offx + offy * offy;
    float se = sg * 2.0f;
    float wgeo = expf(-0.5f * d2 / (se * se + 1e-8f));
    float gate = 1.0f / (1.0f + expf(-g_raw));
    float w = wgeo * gate;
    float wv = (lane < K_TAPS) ? w : 0.0f;
#pragma unroll
    for (int m = 32; m >= 1; m >>= 1) wv += __shfl_xor(wv, m, 64);
    float wn = w / (wv + 1e-8f);
    float acc = 0.0f;
#pragma unroll
    for (int k = 0; k < K_TAPS; ++k) {
        float ox = __shfl(offx, k, 64) * SCLX;
        float oy = __shfl(offy, k, 64) * SCLY;
        float wk2 = __shfl(wn, k, 64);
        float fv = bilin_chw(feat, b, lane, gx + ox, gy + oy);
        acc = fmaf(fv, wk2, acc);
    }
    out[(size_t)pidx * CC + lane] = acc;
}

extern "C" void kernel_launch(void* const* d_in, const int* in_sizes, int n_in,
                              void* d_out, int out_size, void* d_ws, size_t ws_size,
                              hipStream_t stream) {
    const float* feat = (const float*)d_in[0];
    const float* coords = (const float*)d_in[1];
    const float* cell = (const float*)d_in[2];
    const float* W1 = (const float*)d_in[3];
    const float* b1 = (const float*)d_in[4];
    const float* Wr = (const float*)d_in[5];
    const float* br = (const float*)d_in[6];
    const float* W2 = (const float*)d_in[7];
    const float* b2 = (const float*)d_in[8];
    float* out = (float*)d_out;

    const size_t needT = (size_t)BB * HH * WW * CC * sizeof(float);

    if (ws_size >= needT) {
        float* featT = (float*)d_ws;
        dim3 tg((HH * WW) / 64, BB);
        transpose_kernel<<<tg, 256, 0, stream>>>(feat, featT);
        fused_kernel<<<(BB * NN) / 256, 256, 0, stream>>>(
            (const float4*)featT, coords, cell, W1, b1, Wr, br, W2, b2, (float4*)out);
    } else {
        fallback_kernel<<<BB * NN / 4, 256, 0, stream>>>(feat, coords, cell, W1, b1, Wr, br,
                                                         W2, b2, out);
    }
}